// Round 10
// baseline (124.119 us; speedup 1.0000x reference)
//
#include <hip/hip_runtime.h>
#include <hip/hip_bf16.h>
#include <cstdio>

#define S_ 1024
#define H_ 1024
#define NH_ 16
#define DH_ 64
#define G_ 100

typedef __attribute__((ext_vector_type(8))) short bf16x8;
typedef __attribute__((ext_vector_type(4))) short bf16x4;
typedef __attribute__((ext_vector_type(4))) float f32x4;

__device__ __forceinline__ f32x4 mfma16(bf16x8 a, bf16x8 b, f32x4 c) {
  return __builtin_amdgcn_mfma_f32_16x16x32_bf16(a, b, c, 0, 0, 0);
}

// K=16 MFMA: A/B = 4 bf16 (2 VGPRs) per lane.
__device__ __forceinline__ f32x4 mfma16x16(bf16x4 a, bf16x4 b, f32x4 c) {
#if __has_builtin(__builtin_amdgcn_mfma_f32_16x16x16_bf16)
  return __builtin_amdgcn_mfma_f32_16x16x16_bf16(a, b, c, 0, 0, 0);
#elif __has_builtin(__builtin_amdgcn_mfma_f32_16x16x16bf16_1k)
  return __builtin_amdgcn_mfma_f32_16x16x16bf16_1k(a, b, c, 0, 0, 0);
#else
  f32x4 d;
  asm volatile("v_mfma_f32_16x16x16_bf16 %0, %1, %2, %3"
               : "=v"(d)
               : "v"(a), "v"(b), "v"(c));
  return d;
#endif
}

__device__ __forceinline__ short f2bf(float f) {
  union { float f; unsigned int i; } x;
  x.f = f;
  unsigned int r = x.i + 0x7fff + ((x.i >> 16) & 1);  // RNE
  return (short)(r >> 16);
}

// packed f32x2 -> bf16x2 (RNE), gfx950 has no builtin for this (T12 recipe)
__device__ __forceinline__ unsigned cvtpk(float lo, float hi) {
  unsigned r;
  asm("v_cvt_pk_bf16_f32 %0, %1, %2" : "=v"(r) : "v"(lo), "v"(hi));
  return r;
}

// async global->LDS, 16B per lane
__device__ __forceinline__ void gload16(const void* g, void* l) {
  __builtin_amdgcn_global_load_lds(
      (const __attribute__((address_space(1))) unsigned int*)g,
      (__attribute__((address_space(3))) unsigned int*)l, 16, 0, 0);
}

// ------- fp32 -> bf16 convert, up to 3 tensors via blockIdx.y ---------------
__global__ __launch_bounds__(256) void cvt3(
    const float* __restrict__ s0, const float* __restrict__ s1,
    const float* __restrict__ s2, short* __restrict__ d0,
    short* __restrict__ d1, short* __restrict__ d2, int n8) {
  const float* in = (blockIdx.y == 0) ? s0 : (blockIdx.y == 1) ? s1 : s2;
  short* out = (blockIdx.y == 0) ? d0 : (blockIdx.y == 1) ? d1 : d2;
  int i = blockIdx.x * blockDim.x + threadIdx.x;
  if (i >= n8) return;
  f32x4 a = *reinterpret_cast<const f32x4*>(in + (size_t)i * 8);
  f32x4 b = *reinterpret_cast<const f32x4*>(in + (size_t)i * 8 + 4);
  bf16x8 o;
#pragma unroll
  for (int j = 0; j < 4; ++j) {
    o[j] = f2bf(a[j]);
    o[4 + j] = f2bf(b[j]);
  }
  *reinterpret_cast<bf16x8*>(out + (size_t)i * 8) = o;
}

// ------- transpose + fp32->bf16 convert, 4 HxH weights: T[n][k] = W[k][n] ---
__global__ __launch_bounds__(256) void transpose_w(
    const float* __restrict__ W0, const float* __restrict__ W1,
    const float* __restrict__ W2, const float* __restrict__ W3,
    short* __restrict__ T0, short* __restrict__ T1,
    short* __restrict__ T2, short* __restrict__ T3) {
  __shared__ short tile[64][72];
  const float* W = (blockIdx.z == 0) ? W0 : (blockIdx.z == 1) ? W1
                 : (blockIdx.z == 2) ? W2 : W3;
  short* T = (blockIdx.z == 0) ? T0 : (blockIdx.z == 1) ? T1
           : (blockIdx.z == 2) ? T2 : T3;
  const int t = threadIdx.x;
  const int r0 = t >> 3;          // 0..31
  const int c8 = (t & 7) * 8;     // 0..56
  const int kbase = blockIdx.x * 64, nbase = blockIdx.y * 64;
#pragma unroll
  for (int p = 0; p < 2; ++p) {
    int r = p * 32 + r0;
    const float* src = W + (size_t)(kbase + r) * H_ + nbase + c8;
    f32x4 u0 = *reinterpret_cast<const f32x4*>(src);
    f32x4 u1 = *reinterpret_cast<const f32x4*>(src + 4);
#pragma unroll
    for (int j = 0; j < 4; ++j) {
      tile[r][c8 + j] = f2bf(u0[j]);
      tile[r][c8 + 4 + j] = f2bf(u1[j]);
    }
  }
  __syncthreads();
#pragma unroll
  for (int p = 0; p < 2; ++p) {
    int r = p * 32 + r0;          // n offset within tile
    bf16x8 o;
#pragma unroll
    for (int j = 0; j < 8; ++j) o[j] = tile[c8 + j][r];
    *reinterpret_cast<bf16x8*>(T + (size_t)(nbase + r) * H_ + kbase + c8) = o;
  }
}

// ---- QKV GEMM: 128x128 tile, BK=32, 2-phase double-buffered (32KB total),
// global_load_lds staging; frag ds_reads issue BEFORE next-tile stage so the
// barrier's vmcnt drain overlaps compute. 64B row stride = conflict-free.
// z = blockIdx.z (fused) or zsel: 0 -> Qh (scale 1/8, head layout),
// 1 -> Kh (head layout), 2 -> VhT (headT layout).
__global__ __launch_bounds__(256) void qkv128(
    const short* __restrict__ A0, const short* __restrict__ A1,
    const short* __restrict__ A2, const short* __restrict__ W0,
    const short* __restrict__ W1, const short* __restrict__ W2,
    const float* __restrict__ b0, const float* __restrict__ b1,
    const float* __restrict__ b2, short* __restrict__ O0,
    short* __restrict__ O1, short* __restrict__ O2, int zsel) {
  __shared__ short As[2][128 * 32];
  __shared__ short Bs[2][128 * 32];
  const int z = (gridDim.z == 3) ? (int)blockIdx.z : zsel;
  const short* A  = (z == 0) ? A0 : (z == 1) ? A1 : A2;
  const short* Bt = (z == 0) ? W0 : (z == 1) ? W1 : W2;
  const float* bias = (z == 0) ? b0 : (z == 1) ? b1 : b2;
  short* Cb = (z == 0) ? O0 : (z == 1) ? O1 : O2;
  const float scale = (z == 0) ? 0.125f : 1.0f;
  const int K = H_;
  const int t = threadIdx.x;
  const int l = t & 63, w = t >> 6;
  const int lr = l & 15, lg = l >> 4;
  const int wm = w >> 1, wn = w & 1;   // 2x2 waves, each 64x64
  const int bm = blockIdx.x * 128, bn = blockIdx.y * 128;
  f32x4 acc[4][4];
#pragma unroll
  for (int i = 0; i < 4; ++i)
#pragma unroll
    for (int j = 0; j < 4; ++j) acc[i][j] = (f32x4){0.f, 0.f, 0.f, 0.f};
  const int sr = t >> 2;              // 0..63 (stage row)
  const int sc = (t & 3) * 8;         // 0..24 (stage col, 16B group)
  const short* Ab = A + (size_t)(bm + sr) * K + sc;
  const short* Bb = Bt + (size_t)(bn + sr) * K + sc;

  auto stage = [&](int buf, int kb) {
    gload16(Ab + kb, &As[buf][t * 8]);
    gload16(Ab + (size_t)64 * K + kb, &As[buf][2048 + t * 8]);
    gload16(Bb + kb, &Bs[buf][t * 8]);
    gload16(Bb + (size_t)64 * K + kb, &Bs[buf][2048 + t * 8]);
  };

  stage(0, 0);
  __syncthreads();
  const int NT = K >> 5;
  int cur = 0;
  for (int tt = 0; tt < NT; ++tt) {
    bf16x8 af[4], bfr[4];
#pragma unroll
    for (int mi = 0; mi < 4; ++mi)
      af[mi] = *reinterpret_cast<const bf16x8*>(
          &As[cur][(wm * 64 + mi * 16 + lr) * 32 + lg * 8]);
#pragma unroll
    for (int ni = 0; ni < 4; ++ni)
      bfr[ni] = *reinterpret_cast<const bf16x8*>(
          &Bs[cur][(wn * 64 + ni * 16 + lr) * 32 + lg * 8]);
    if (tt + 1 < NT) stage(cur ^ 1, (tt + 1) << 5);
#pragma unroll
    for (int mi = 0; mi < 4; ++mi)
#pragma unroll
      for (int ni = 0; ni < 4; ++ni)
        acc[mi][ni] = mfma16(af[mi], bfr[ni], acc[mi][ni]);
    __syncthreads();   // drains vmcnt: next tile landed; all done reading cur
    cur ^= 1;
  }
#pragma unroll
  for (int mi = 0; mi < 4; ++mi)
#pragma unroll
    for (int ni = 0; ni < 4; ++ni) {
      int col = bn + wn * 64 + ni * 16 + lr;   // 0..1023 (global n)
      float bv = bias[col];
      int h = col >> 6, d = col & 63;
      if (z == 2) {                            // headT, packed s-contiguous
        int row0 = bm + wm * 64 + mi * 16 + lg * 4;
        int b = row0 >> 10, s0 = row0 & 1023;
        bf16x4 pk;
#pragma unroll
        for (int r = 0; r < 4; ++r) pk[r] = f2bf(acc[mi][ni][r] + bv);
        *reinterpret_cast<bf16x4*>(
            Cb + (((size_t)(b * NH_ + h)) * DH_ + d) * S_ + s0) = pk;
      } else {                                 // head layout [B,NH,S,DH]
#pragma unroll
        for (int r = 0; r < 4; ++r) {
          int row = bm + wm * 64 + mi * 16 + lg * 4 + r;
          int b = row >> 10, s = row & 1023;
          Cb[(((size_t)(b * NH_ + h)) * S_ + s) * DH_ + d] =
              f2bf((acc[mi][ni][r] + bv) * scale);
        }
      }
    }
}

// ---- out GEMM: 64x128 tile, BK=32, 2-phase double-buffered (24KB),
// fp32 output ---------------------------------------------------------------
__global__ __launch_bounds__(256) void out64(
    const short* __restrict__ A, const short* __restrict__ Bt,
    const float* __restrict__ bias, float* __restrict__ Cf) {
  __shared__ short As[2][64 * 32];
  __shared__ short Bs[2][128 * 32];
  const int K = H_, N = H_;
  const int t = threadIdx.x;
  const int l = t & 63, w = t >> 6;
  const int lr = l & 15, lg = l >> 4;
  const int wm = w >> 1, wn = w & 1;   // 2x2 waves, each 32x64
  const int bm = blockIdx.x * 64, bn = blockIdx.y * 128;
  f32x4 acc[2][4];
#pragma unroll
  for (int i = 0; i < 2; ++i)
#pragma unroll
    for (int j = 0; j < 4; ++j) acc[i][j] = (f32x4){0.f, 0.f, 0.f, 0.f};
  const int sr = t >> 2;              // 0..63
  const int sc = (t & 3) * 8;
  const short* Ab = A + (size_t)(bm + sr) * K + sc;
  const short* Bb = Bt + (size_t)(bn + sr) * K + sc;

  auto stage = [&](int buf, int kb) {
    gload16(Ab + kb, &As[buf][t * 8]);
    gload16(Bb + kb, &Bs[buf][t * 8]);
    gload16(Bb + (size_t)64 * K + kb, &Bs[buf][2048 + t * 8]);
  };

  stage(0, 0);
  __syncthreads();
  const int NT = K >> 5;
  int cur = 0;
  for (int tt = 0; tt < NT; ++tt) {
    bf16x8 af[2], bfr[4];
#pragma unroll
    for (int mi = 0; mi < 2; ++mi)
      af[mi] = *reinterpret_cast<const bf16x8*>(
          &As[cur][(wm * 32 + mi * 16 + lr) * 32 + lg * 8]);
#pragma unroll
    for (int ni = 0; ni < 4; ++ni)
      bfr[ni] = *reinterpret_cast<const bf16x8*>(
          &Bs[cur][(wn * 64 + ni * 16 + lr) * 32 + lg * 8]);
    if (tt + 1 < NT) stage(cur ^ 1, (tt + 1) << 5);
#pragma unroll
    for (int mi = 0; mi < 2; ++mi)
#pragma unroll
      for (int ni = 0; ni < 4; ++ni)
        acc[mi][ni] = mfma16(af[mi], bfr[ni], acc[mi][ni]);
    __syncthreads();
    cur ^= 1;
  }
#pragma unroll
  for (int mi = 0; mi < 2; ++mi)
#pragma unroll
    for (int ni = 0; ni < 4; ++ni) {
      int col = bn + wn * 64 + ni * 16 + lr;
      float bv = bias[col];
#pragma unroll
      for (int r = 0; r < 4; ++r) {
        int row = bm + wm * 32 + mi * 16 + lg * 4 + r;
        Cf[(size_t)row * N + col] = acc[mi][ni][r] + bv;
      }
    }
}

// ---------------- flash attention, max-free softmax, in-register P ----------
// Qh (pre-scaled by 1/8), Kh: [B*NH][S][DH] bf16; VhT: [B*NH][DH][S] bf16.
// p = exp(s + mk), mk = masked ? -1e9 : -16*ln2 (shift cancels in p/sum).
// PV uses 16x16x16 MFMA: swapped-QK output (lane holds P[k=mf*16+lg*4+r][q=lr])
// IS the K=16 A-fragment (A[row=lr][k=lg*4+i]) -> no P LDS roundtrip at all.
__global__ __launch_bounds__(256) void attn(
    const short* __restrict__ Qh, const short* __restrict__ Kh,
    const short* __restrict__ VhT, const float* __restrict__ graph,
    const int* __restrict__ mask, short* __restrict__ ctx) {
  __shared__ short Kb[64 * 64];
  __shared__ short Vb[64 * 64];
  __shared__ float maskf[S_];
  // T1 chunked XCD swizzle: 8 XCDs x 128 contiguous gids
  const int lin = blockIdx.x;
  const int gid = (lin & 7) * 128 + (lin >> 3);
  const int bh = gid >> 4, qt = gid & 15;
  const int b = bh >> 4, h = bh & 15;
  const int t = threadIdx.x, w = t >> 6, l = t & 63;
  const int lr = l & 15, lg = l >> 4;
  const int lx = lr & 7;
  const int q0 = qt * 64 + w * 16;      // this wave's q base
  const int qg = q0 + lr;               // lane's q (score layout: col = q)
  const short* Qrow = Qh + ((size_t)bh * S_ + qg) * DH_;
  bf16x8 qf0 = *reinterpret_cast<const bf16x8*>(Qrow + lg * 8);
  bf16x8 qf1 = *reinterpret_cast<const bf16x8*>(Qrow + 32 + lg * 8);
  f32x4 o[4];
#pragma unroll
  for (int i = 0; i < 4; ++i) o[i] = (f32x4){0.f, 0.f, 0.f, 0.f};
  float llp = 0.f;

  // staging geometry: thread t handles row rs, 16B col-groups g0 and g0+4
  const int rs = t >> 2;               // 0..63
  const int g0 = t & 3;                // 0..3
  const int sw0 = ((g0 ^ (rs & 7)) * 8);
  const int sw1 = (((g0 + 4) ^ (rs & 7)) * 8);
  const short* Ksrc = Kh + ((size_t)bh * S_ + rs) * DH_ + g0 * 8;
  const short* Vsrc = VhT + ((size_t)bh * DH_ + rs) * S_ + g0 * 8;

  // mask -> additive table: masked -> -1e9 (exp -> exactly 0),
  // else -16*ln2 (uniform shift, cancels in the final divide)
  {
    int4 mv = reinterpret_cast<const int4*>(mask + b * S_)[t];
    f32x4 mo;
    const float C = -11.0903549f;      // -16*ln2
    mo.x = mv.x ? -1.0e9f : C;
    mo.y = mv.y ? -1.0e9f : C;
    mo.z = mv.z ? -1.0e9f : C;
    mo.w = mv.w ? -1.0e9f : C;
    reinterpret_cast<f32x4*>(maskf)[t] = mo;
  }
  // stage chunk 0
  {
    int4 ka = *reinterpret_cast<const int4*>(Ksrc);
    int4 kb2 = *reinterpret_cast<const int4*>(Ksrc + 32);
    int4 va = *reinterpret_cast<const int4*>(Vsrc);
    int4 vb2 = *reinterpret_cast<const int4*>(Vsrc + 32);
    *reinterpret_cast<int4*>(&Kb[rs * 64 + sw0]) = ka;
    *reinterpret_cast<int4*>(&Kb[rs * 64 + sw1]) = kb2;
    *reinterpret_cast<int4*>(&Vb[rs * 64 + sw0]) = va;
    *reinterpret_cast<int4*>(&Vb[rs * 64 + sw1]) = vb2;
  }
  __syncthreads();

  for (int kc = 0; kc < S_; kc += 64) {
    const bool pf = (kc + 64 < S_);
    int4 ka, kb2, va, vb2;
    if (pf) {                     // prefetch next chunk into registers (T14)
      ka = *reinterpret_cast<const int4*>(Ksrc + (size_t)(kc + 64) * DH_);
      kb2 = *reinterpret_cast<const int4*>(Ksrc + (size_t)(kc + 64) * DH_ + 32);
      va = *reinterpret_cast<const int4*>(Vsrc + kc + 64);
      vb2 = *reinterpret_cast<const int4*>(Vsrc + kc + 64 + 32);
    }
    // --- swapped QK^T from LDS: lane holds q=lr, k = mf*16+lg*4+r
    f32x4 sacc[4];
    __builtin_amdgcn_s_setprio(1);
#pragma unroll
    for (int mf = 0; mf < 4; ++mf) {
      const int rk = mf * 16 + lr;
      bf16x8 k0 = *reinterpret_cast<const bf16x8*>(
          &Kb[rk * 64 + ((lg ^ lx) * 8)]);
      bf16x8 k1 = *reinterpret_cast<const bf16x8*>(
          &Kb[rk * 64 + (((4 + lg) ^ lx) * 8)]);
      f32x4 sa = (f32x4){0.f, 0.f, 0.f, 0.f};
      sa = mfma16(k0, qf0, sa);
      sa = mfma16(k1, qf1, sa);
      sacc[mf] = sa;
    }
    __builtin_amdgcn_s_setprio(0);
    // --- graph factor, additive mask, fixed-shift exp, pack A-fragments
    const bool gblk = (q0 < G_) && (kc < G_);
    bf16x4 pa[4];
#pragma unroll
    for (int mf = 0; mf < 4; ++mf) {
      f32x4 mk = *reinterpret_cast<const f32x4*>(&maskf[kc + mf * 16 + lg * 4]);
      f32x4 sa = sacc[mf];
      if (gblk) {
#pragma unroll
        for (int r = 0; r < 4; ++r) {
          int kg = kc + mf * 16 + lg * 4 + r;
          if (qg < G_ && kg < G_)
            sa[r] *= (1.f - graph[((size_t)b * G_ + qg) * G_ + kg]);
        }
      }
      float e0 = __expf(sa[0] + mk[0]);
      float e1 = __expf(sa[1] + mk[1]);
      float e2 = __expf(sa[2] + mk[2]);
      float e3 = __expf(sa[3] + mk[3]);
      llp += (e0 + e1) + (e2 + e3);
      union { unsigned u[2]; bf16x4 v; } pk2;
      pk2.u[0] = cvtpk(e0, e1);
      pk2.u[1] = cvtpk(e2, e3);
      pa[mf] = pk2.v;
    }
    // --- PV via 16x16x16: O[q=lg*4+r][d=nf*16+lr] += P[q][k] V[k][d]
    __builtin_amdgcn_s_setprio(1);
#pragma unroll
    for (int mf = 0; mf < 4; ++mf) {
      const int co = (((2 * mf + (lg >> 1)) ^ lx) * 8) + (lg & 1) * 4;
#pragma unroll
      for (int nf = 0; nf < 4; ++nf) {
        bf16x4 vb4 = *reinterpret_cast<const bf16x4*>(
            &Vb[(nf * 16 + lr) * 64 + co]);
        o[nf] = mfma16x16(pa[mf], vb4, o[nf]);
      }
    }
    __builtin_amdgcn_s_setprio(0);
    if (pf) {
      __syncthreads();   // all waves done reading Kb/Vb for this chunk
      *reinterpret_cast<int4*>(&Kb[rs * 64 + sw0]) = ka;
      *reinterpret_cast<int4*>(&Kb[rs * 64 + sw1]) = kb2;
      *reinterpret_cast<int4*>(&Vb[rs * 64 + sw0]) = va;
      *reinterpret_cast<int4*>(&Vb[rs * 64 + sw1]) = vb2;
      __syncthreads();   // staged data visible
    }
  }
  // single cross-lane reduction at the end
  llp += __shfl_xor(llp, 16);
  llp += __shfl_xor(llp, 32);
  float rinv[4];
#pragma unroll
  for (int r = 0; r < 4; ++r)
    rinv[r] = __builtin_amdgcn_rcpf(__shfl(llp, lg * 4 + r, 64));
#pragma unroll
  for (int nf = 0; nf < 4; ++nf)
#pragma unroll
    for (int r = 0; r < 4; ++r) {
      float val = o[nf][r] * rinv[r];
      ctx[((size_t)b * S_ + q0 + lg * 4 + r) * H_ + h * DH_ + nf * 16 + lr] =
          f2bf(val);
    }
}

extern "C" void kernel_launch(void* const* d_in, const int* in_sizes, int n_in,
                              void* d_out, int out_size, void* d_ws, size_t ws_size,
                              hipStream_t stream) {
  const int B = in_sizes[0] / (S_ * H_);   // 4
  const int M = B * S_;                    // 4096
  const float* v    = (const float*)d_in[0];
  const float* k    = (const float*)d_in[1];
  const float* q    = (const float*)d_in[2];
  const int*   mask = (const int*)d_in[3];
  const float* graph= (const float*)d_in[4];
  const float* Wq   = (const float*)d_in[5];
  const float* bq   = (const float*)d_in[6];
  const float* Wk   = (const float*)d_in[7];
  const float* bk   = (const float*)d_in[8];
  const float* Wv   = (const float*)d_in[9];
  const float* bv   = (const float*)d_in[10];
  const float* Wm   = (const float*)d_in[11];
  const float* bm   = (const float*)d_in[12];

  short* ws = (short*)d_ws;
  const size_t WSZ = (size_t)H_ * H_;     // 1M elems per transposed weight
  const size_t TSZ = (size_t)M * H_;      // 4M elems per activation tensor
  short* WqT = ws;
  short* WkT = ws + WSZ;
  short* WvT = ws + 2 * WSZ;
  short* WmT = ws + 3 * WSZ;
  short* base = ws + 4 * WSZ;
  if (ws_size < (4 * WSZ + 4 * TSZ) * sizeof(short)) {
    fprintf(stderr, "kernel_launch: ws too small (%zu)\n", ws_size);
    return;
  }
  const int n8 = (int)(TSZ / 8);
  const int cvg = (n8 + 255) / 256;

  transpose_w<<<dim3(H_ / 64, H_ / 64, 4), 256, 0, stream>>>(
      Wq, Wk, Wv, Wm, WqT, WkT, WvT, WmT);

  if (ws_size >= (4 * WSZ + 6 * TSZ) * sizeof(short)) {
    // fused path: 3 converted inputs live at once
    short* Aq = base;
    short* Ak = base + TSZ;
    short* Av = base + 2 * TSZ;
    short* Qh = base + 3 * TSZ;
    short* Kh = base + 4 * TSZ;
    short* VhT = base + 5 * TSZ;
    short* ctx = Aq;                      // dead after qkv128
    cvt3<<<dim3(cvg, 3), 256, 0, stream>>>(q, k, v, Aq, Ak, Av, n8);
    qkv128<<<dim3(M / 128, H_ / 128, 3), 256, 0, stream>>>(
        Aq, Ak, Av, WqT, WkT, WvT, bq, bk, bv, Qh, Kh, VhT, 0);
    attn<<<dim3(1024), 256, 0, stream>>>(Qh, Kh, VhT, graph, mask, ctx);
    out64<<<dim3(M / 64, H_ / 128), 256, 0, stream>>>(
        ctx, WmT, bm, (float*)d_out);
  } else {
    // sequential path: single shared A buffer
    short* AB = base;
    short* Qh = base + TSZ;
    short* Kh = base + 2 * TSZ;
    short* VhT = base + 3 * TSZ;
    cvt3<<<dim3(cvg, 1), 256, 0, stream>>>(q, q, q, AB, AB, AB, n8);
    qkv128<<<dim3(M / 128, H_ / 128, 1), 256, 0, stream>>>(
        AB, AB, AB, WqT, WkT, WvT, bq, bk, bv, Qh, Kh, VhT, 0);
    cvt3<<<dim3(cvg, 1), 256, 0, stream>>>(k, k, k, AB, AB, AB, n8);
    qkv128<<<dim3(M / 128, H_ / 128, 1), 256, 0, stream>>>(
        AB, AB, AB, WqT, WkT, WvT, bq, bk, bv, Qh, Kh, VhT, 1);
    cvt3<<<dim3(cvg, 1), 256, 0, stream>>>(v, v, v, AB, AB, AB, n8);
    qkv128<<<dim3(M / 128, H_ / 128, 1), 256, 0, stream>>>(
        AB, AB, AB, WqT, WkT, WvT, bq, bk, bv, Qh, Kh, VhT, 2);
    attn<<<dim3(1024), 256, 0, stream>>>(Qh, Kh, VhT, graph, mask, AB);
    out64<<<dim3(M / 64, H_ / 128), 256, 0, stream>>>(
        AB, WmT, bm, (float*)d_out);
  }
}

// Round 11
// 105.463 us; speedup vs baseline: 1.1769x; 1.1769x over previous
//
#include <hip/hip_runtime.h>
#include <hip/hip_bf16.h>
#include <cstdio>

#define S_ 1024
#define H_ 1024
#define NH_ 16
#define DH_ 64
#define G_ 100

typedef __attribute__((ext_vector_type(8))) short bf16x8;
typedef __attribute__((ext_vector_type(4))) short bf16x4;
typedef __attribute__((ext_vector_type(4))) float f32x4;

__device__ __forceinline__ f32x4 mfma16(bf16x8 a, bf16x8 b, f32x4 c) {
  return __builtin_amdgcn_mfma_f32_16x16x32_bf16(a, b, c, 0, 0, 0);
}

__device__ __forceinline__ short f2bf(float f) {
  union { float f; unsigned int i; } x;
  x.f = f;
  unsigned int r = x.i + 0x7fff + ((x.i >> 16) & 1);  // RNE
  return (short)(r >> 16);
}

// packed f32x2 -> bf16x2, gfx950 hardware instruction (T12 recipe)
__device__ __forceinline__ unsigned cvtpk(float lo, float hi) {
  unsigned r;
  asm("v_cvt_pk_bf16_f32 %0, %1, %2" : "=v"(r) : "v"(lo), "v"(hi));
  return r;
}

// async global->LDS, 16B per lane
__device__ __forceinline__ void gload16(const void* g, void* l) {
  __builtin_amdgcn_global_load_lds(
      (const __attribute__((address_space(1))) unsigned int*)g,
      (__attribute__((address_space(3))) unsigned int*)l, 16, 0, 0);
}

// ------- transpose + fp32->bf16 convert, 4 HxH weights: T[n][k] = W[k][n] ---
__global__ __launch_bounds__(256) void transpose_w(
    const float* __restrict__ W0, const float* __restrict__ W1,
    const float* __restrict__ W2, const float* __restrict__ W3,
    short* __restrict__ T0, short* __restrict__ T1,
    short* __restrict__ T2, short* __restrict__ T3) {
  __shared__ short tile[64][72];
  const float* W = (blockIdx.z == 0) ? W0 : (blockIdx.z == 1) ? W1
                 : (blockIdx.z == 2) ? W2 : W3;
  short* T = (blockIdx.z == 0) ? T0 : (blockIdx.z == 1) ? T1
           : (blockIdx.z == 2) ? T2 : T3;
  const int t = threadIdx.x;
  const int r0 = t >> 3;          // 0..31
  const int c8 = (t & 7) * 8;     // 0..56
  const int kbase = blockIdx.x * 64, nbase = blockIdx.y * 64;
#pragma unroll
  for (int p = 0; p < 2; ++p) {
    int r = p * 32 + r0;
    const float* src = W + (size_t)(kbase + r) * H_ + nbase + c8;
    f32x4 u0 = *reinterpret_cast<const f32x4*>(src);
    f32x4 u1 = *reinterpret_cast<const f32x4*>(src + 4);
#pragma unroll
    for (int j = 0; j < 4; ++j) {
      tile[r][c8 + j] = f2bf(u0[j]);
      tile[r][c8 + 4 + j] = f2bf(u1[j]);
    }
  }
  __syncthreads();
#pragma unroll
  for (int p = 0; p < 2; ++p) {
    int r = p * 32 + r0;          // n offset within tile
    bf16x8 o;
#pragma unroll
    for (int j = 0; j < 8; ++j) o[j] = tile[c8 + j][r];
    *reinterpret_cast<bf16x8*>(T + (size_t)(nbase + r) * H_ + kbase + c8) = o;
  }
}

// ---- QKV GEMM, fp32-A direct: 128x128 tile, BK=64, single-buffered 48KB.
// A staged as RAW FP32 via global_load_lds (no cvt pass, no reg staging);
// source groups pre-swizzled on low-3 bits (T2/rule#21); fragments converted
// in-register with v_cvt_pk_bf16_f32 at read time. B (bf16 weights) staged
// as in round 9 (pre-swizzled source, 0 conflicts measured).
// z: 0 -> Qh (scale 1/8, head layout), 1 -> Kh (head layout), 2 -> VhT.
__global__ __launch_bounds__(256, 3) void qkv128f(
    const float* __restrict__ A0, const float* __restrict__ A1,
    const float* __restrict__ A2, const short* __restrict__ W0,
    const short* __restrict__ W1, const short* __restrict__ W2,
    const float* __restrict__ b0, const float* __restrict__ b1,
    const float* __restrict__ b2, short* __restrict__ O0,
    short* __restrict__ O1, short* __restrict__ O2) {
  __shared__ float Af[128 * 64];   // 32 KB, fp32 A tile, 16 16B-slots/row
  __shared__ short Bs[128 * 64];   // 16 KB
  const int z = blockIdx.z;
  const float* A  = (z == 0) ? A0 : (z == 1) ? A1 : A2;
  const short* Bt = (z == 0) ? W0 : (z == 1) ? W1 : W2;
  const float* bias = (z == 0) ? b0 : (z == 1) ? b1 : b2;
  short* Cb = (z == 0) ? O0 : (z == 1) ? O1 : O2;
  const float scale = (z == 0) ? 0.125f : 1.0f;
  const int K = H_;
  const int t = threadIdx.x;
  const int l = t & 63, w = t >> 6;
  const int lr = l & 15, lg = l >> 4;
  const int lx = lr & 7;
  const int wm = w >> 1, wn = w & 1;   // 2x2 waves, each 64x64
  const int bm = blockIdx.x * 128, bn = blockIdx.y * 128;
  f32x4 acc[4][4];
#pragma unroll
  for (int i = 0; i < 4; ++i)
#pragma unroll
    for (int j = 0; j < 4; ++j) acc[i][j] = (f32x4){0.f, 0.f, 0.f, 0.f};

  // A staging: thread t -> row ar = t>>4 (per 16-row pass), slot group t&15.
  // Slot (row,g) holds global group (g&8)|((g&7)^(row&7)).
  const int ar = t >> 4;              // 0..15
  const int ag = t & 15;
  const int asg = (ag & 8) | ((ag & 7) ^ (ar & 7));
  const float* Ab = A + (size_t)(bm + ar) * K + asg * 4;
  // B staging: thread t -> row t>>3 (per 32-row pass), pre-swizzled 16B group
  const int br = t >> 3;              // 0..31
  const int bsc = ((t & 7) ^ (br & 7)) * 8;
  const short* Bb = Bt + (size_t)(bn + br) * K + bsc;

  for (int kb = 0; kb < K; kb += 64) {
#pragma unroll
    for (int p = 0; p < 8; ++p)
      gload16(Ab + (size_t)p * 16 * K + kb,
              (char*)Af + p * 4096 + t * 16);
#pragma unroll
    for (int i = 0; i < 4; ++i)
      gload16(Bb + (size_t)i * 32 * K + kb,
              (char*)Bs + i * 4096 + t * 16);
    __syncthreads();
#pragma unroll
    for (int ks = 0; ks < 2; ++ks) {
      bf16x8 af[4], bfr[4];
#pragma unroll
      for (int mi = 0; mi < 4; ++mi) {
        const int row = wm * 64 + mi * 16 + lr;
        const int s0 = (ks * 8) | ((lg * 2) ^ lx);
        f32x4 alo = *reinterpret_cast<const f32x4*>(&Af[row * 64 + s0 * 4]);
        f32x4 ahi =
            *reinterpret_cast<const f32x4*>(&Af[row * 64 + (s0 ^ 1) * 4]);
        union { unsigned u[4]; bf16x8 v; } c;
        c.u[0] = cvtpk(alo[0], alo[1]);
        c.u[1] = cvtpk(alo[2], alo[3]);
        c.u[2] = cvtpk(ahi[0], ahi[1]);
        c.u[3] = cvtpk(ahi[2], ahi[3]);
        af[mi] = c.v;
      }
#pragma unroll
      for (int ni = 0; ni < 4; ++ni)
        bfr[ni] = *reinterpret_cast<const bf16x8*>(
            &Bs[(wn * 64 + ni * 16 + lr) * 64 + (((ks * 4 + lg) ^ lx) * 8)]);
#pragma unroll
      for (int mi = 0; mi < 4; ++mi)
#pragma unroll
        for (int ni = 0; ni < 4; ++ni)
          acc[mi][ni] = mfma16(af[mi], bfr[ni], acc[mi][ni]);
    }
    __syncthreads();
  }
#pragma unroll
  for (int mi = 0; mi < 4; ++mi)
#pragma unroll
    for (int ni = 0; ni < 4; ++ni) {
      int col = bn + wn * 64 + ni * 16 + lr;   // 0..1023 (global n)
      float bv = bias[col];
      int h = col >> 6, d = col & 63;
      if (z == 2) {                            // headT, packed s-contiguous
        int row0 = bm + wm * 64 + mi * 16 + lg * 4;
        int b = row0 >> 10, s0 = row0 & 1023;
        bf16x4 pk;
#pragma unroll
        for (int r = 0; r < 4; ++r) pk[r] = f2bf(acc[mi][ni][r] + bv);
        *reinterpret_cast<bf16x4*>(
            Cb + (((size_t)(b * NH_ + h)) * DH_ + d) * S_ + s0) = pk;
      } else {                                 // head layout [B,NH,S,DH]
#pragma unroll
        for (int r = 0; r < 4; ++r) {
          int row = bm + wm * 64 + mi * 16 + lg * 4 + r;
          int b = row >> 10, s = row & 1023;
          Cb[(((size_t)(b * NH_ + h)) * S_ + s) * DH_ + d] =
              f2bf((acc[mi][ni][r] + bv) * scale);
        }
      }
    }
}

// ---- out GEMM: 64x128 tile, BK=64, single-buffered 24KB, T2 swizzle,
// fp32 output (round-9 proven) ----------------------------------------------
__global__ __launch_bounds__(256) void out64(
    const short* __restrict__ A, const short* __restrict__ Bt,
    const float* __restrict__ bias, float* __restrict__ Cf) {
  __shared__ short As[64 * 64];
  __shared__ short Bs[128 * 64];
  const int K = H_, N = H_;
  const int t = threadIdx.x;
  const int l = t & 63, w = t >> 6;
  const int lr = l & 15, lg = l >> 4;
  const int lx = lr & 7;
  const int wm = w >> 1, wn = w & 1;   // 2x2 waves, each 32x64
  const int bm = blockIdx.x * 64, bn = blockIdx.y * 128;
  f32x4 acc[2][4];
#pragma unroll
  for (int i = 0; i < 2; ++i)
#pragma unroll
    for (int j = 0; j < 4; ++j) acc[i][j] = (f32x4){0.f, 0.f, 0.f, 0.f};
  const int sr = t >> 3;              // 0..31
  const int ssc = ((t & 7) ^ (sr & 7)) * 8;   // pre-swizzled source colgroup
  const short* Ab = A + (size_t)(bm + sr) * K + ssc;
  const short* Bb = Bt + (size_t)(bn + sr) * K + ssc;
  short* la = As + t * 8;
  short* lb = Bs + t * 8;

  for (int kb = 0; kb < K; kb += 64) {
#pragma unroll
    for (int i = 0; i < 2; ++i)
      gload16(Ab + (size_t)i * 32 * K + kb, la + i * 2048);
#pragma unroll
    for (int i = 0; i < 4; ++i)
      gload16(Bb + (size_t)i * 32 * K + kb, lb + i * 2048);
    __syncthreads();
#pragma unroll
    for (int ks = 0; ks < 2; ++ks) {
      bf16x8 af[2], bfr[4];
#pragma unroll
      for (int mi = 0; mi < 2; ++mi)
        af[mi] = *reinterpret_cast<const bf16x8*>(
            &As[(wm * 32 + mi * 16 + lr) * 64 + (((ks * 4 + lg) ^ lx) * 8)]);
#pragma unroll
      for (int ni = 0; ni < 4; ++ni)
        bfr[ni] = *reinterpret_cast<const bf16x8*>(
            &Bs[(wn * 64 + ni * 16 + lr) * 64 + (((ks * 4 + lg) ^ lx) * 8)]);
#pragma unroll
      for (int mi = 0; mi < 2; ++mi)
#pragma unroll
        for (int ni = 0; ni < 4; ++ni)
          acc[mi][ni] = mfma16(af[mi], bfr[ni], acc[mi][ni]);
    }
    __syncthreads();
  }
#pragma unroll
  for (int mi = 0; mi < 2; ++mi)
#pragma unroll
    for (int ni = 0; ni < 4; ++ni) {
      int col = bn + wn * 64 + ni * 16 + lr;
      float bv = bias[col];
#pragma unroll
      for (int r = 0; r < 4; ++r) {
        int row = bm + wm * 32 + mi * 16 + lg * 4 + r;
        Cf[(size_t)row * N + col] = acc[mi][ni][r] + bv;
      }
    }
}

// ---------------- flash attention, max-free softmax (round-9 proven) --------
// Qh (pre-scaled by 1/8), Kh: [B*NH][S][DH] bf16; VhT: [B*NH][DH][S] bf16.
// p = exp(s + mk), mk = masked ? -1e9 : -16*ln2 (shift cancels in p/sum).
__global__ __launch_bounds__(256) void attn(
    const short* __restrict__ Qh, const short* __restrict__ Kh,
    const short* __restrict__ VhT, const float* __restrict__ graph,
    const int* __restrict__ mask, short* __restrict__ ctx) {
  __shared__ short Kb[64 * 64];
  __shared__ short Vb[64 * 64];
  __shared__ short P[4 * 16 * 64];   // per-wave 16x64, XOR-swizzled, stride 64
  __shared__ float maskf[S_];
  // T1 chunked XCD swizzle: 8 XCDs x 128 contiguous gids
  const int lin = blockIdx.x;
  const int gid = (lin & 7) * 128 + (lin >> 3);
  const int bh = gid >> 4, qt = gid & 15;
  const int b = bh >> 4, h = bh & 15;
  const int t = threadIdx.x, w = t >> 6, l = t & 63;
  const int lr = l & 15, lg = l >> 4;
  const int lx = lr & 7;
  const int q0 = qt * 64 + w * 16;      // this wave's q base
  const int qg = q0 + lr;               // lane's q (score layout: col = q)
  short* Pw = P + w * 1024;
  const short* Qrow = Qh + ((size_t)bh * S_ + qg) * DH_;
  bf16x8 qf0 = *reinterpret_cast<const bf16x8*>(Qrow + lg * 8);
  bf16x8 qf1 = *reinterpret_cast<const bf16x8*>(Qrow + 32 + lg * 8);
  f32x4 o[4];
#pragma unroll
  for (int i = 0; i < 4; ++i) o[i] = (f32x4){0.f, 0.f, 0.f, 0.f};
  float llp = 0.f;

  // staging geometry: thread t handles row rs, 16B col-groups g0 and g0+4
  const int rs = t >> 2;               // 0..63
  const int g0 = t & 3;                // 0..3
  const int sw0 = ((g0 ^ (rs & 7)) * 8);
  const int sw1 = (((g0 + 4) ^ (rs & 7)) * 8);
  const short* Ksrc = Kh + ((size_t)bh * S_ + rs) * DH_ + g0 * 8;
  const short* Vsrc = VhT + ((size_t)bh * DH_ + rs) * S_ + g0 * 8;

  // mask -> additive table: masked -> -1e9 (exp -> exactly 0),
  // else -16*ln2 (uniform shift, cancels in the final divide)
  {
    int4 mv = reinterpret_cast<const int4*>(mask + b * S_)[t];
    f32x4 mo;
    const float C = -11.0903549f;      // -16*ln2
    mo.x = mv.x ? -1.0e9f : C;
    mo.y = mv.y ? -1.0e9f : C;
    mo.z = mv.z ? -1.0e9f : C;
    mo.w = mv.w ? -1.0e9f : C;
    reinterpret_cast<f32x4*>(maskf)[t] = mo;
  }
  // stage chunk 0
  {
    int4 ka = *reinterpret_cast<const int4*>(Ksrc);
    int4 kb2 = *reinterpret_cast<const int4*>(Ksrc + 32);
    int4 va = *reinterpret_cast<const int4*>(Vsrc);
    int4 vb2 = *reinterpret_cast<const int4*>(Vsrc + 32);
    *reinterpret_cast<int4*>(&Kb[rs * 64 + sw0]) = ka;
    *reinterpret_cast<int4*>(&Kb[rs * 64 + sw1]) = kb2;
    *reinterpret_cast<int4*>(&Vb[rs * 64 + sw0]) = va;
    *reinterpret_cast<int4*>(&Vb[rs * 64 + sw1]) = vb2;
  }
  __syncthreads();

  for (int kc = 0; kc < S_; kc += 64) {
    const bool pf = (kc + 64 < S_);
    int4 ka, kb2, va, vb2;
    if (pf) {                     // prefetch next chunk into registers (T14)
      ka = *reinterpret_cast<const int4*>(Ksrc + (size_t)(kc + 64) * DH_);
      kb2 = *reinterpret_cast<const int4*>(Ksrc + (size_t)(kc + 64) * DH_ + 32);
      va = *reinterpret_cast<const int4*>(Vsrc + kc + 64);
      vb2 = *reinterpret_cast<const int4*>(Vsrc + kc + 64 + 32);
    }
    // --- swapped QK^T from LDS: lane holds q=lr, k = mf*16+lg*4+r
    f32x4 sacc[4];
    __builtin_amdgcn_s_setprio(1);
#pragma unroll
    for (int mf = 0; mf < 4; ++mf) {
      const int rk = mf * 16 + lr;
      bf16x8 k0 = *reinterpret_cast<const bf16x8*>(
          &Kb[rk * 64 + ((lg ^ lx) * 8)]);
      bf16x8 k1 = *reinterpret_cast<const bf16x8*>(
          &Kb[rk * 64 + (((4 + lg) ^ lx) * 8)]);
      f32x4 sa = (f32x4){0.f, 0.f, 0.f, 0.f};
      sa = mfma16(k0, qf0, sa);
      sa = mfma16(k1, qf1, sa);
      sacc[mf] = sa;
    }
    __builtin_amdgcn_s_setprio(0);
    // --- graph factor, additive mask, fixed-shift exp, pack to P
    const bool gblk = (q0 < G_) && (kc < G_);
    const int pw0 = lr * 64 + (lg & 1) * 4;
#pragma unroll
    for (int mf = 0; mf < 4; ++mf) {
      f32x4 mk = *reinterpret_cast<const f32x4*>(&maskf[kc + mf * 16 + lg * 4]);
      f32x4 sa = sacc[mf];
      if (gblk) {
#pragma unroll
        for (int r = 0; r < 4; ++r) {
          int kg = kc + mf * 16 + lg * 4 + r;
          if (qg < G_ && kg < G_)
            sa[r] *= (1.f - graph[((size_t)b * G_ + qg) * G_ + kg]);
        }
      }
      float e0 = __expf(sa[0] + mk[0]);
      float e1 = __expf(sa[1] + mk[1]);
      float e2 = __expf(sa[2] + mk[2]);
      float e3 = __expf(sa[3] + mk[3]);
      llp += (e0 + e1) + (e2 + e3);
      int2 pk2;
      pk2.x = (int)cvtpk(e0, e1);
      pk2.y = (int)cvtpk(e2, e3);
      *reinterpret_cast<int2*>(
          &Pw[pw0 + (((2 * mf + (lg >> 1)) ^ lx) * 8)]) = pk2;
    }
    // --- PV from LDS: O[16q][64d] += P[16q,64k] @ V[64k,64d]
    __builtin_amdgcn_s_setprio(1);
#pragma unroll
    for (int ks = 0; ks < 2; ++ks) {
      bf16x8 pa = *reinterpret_cast<const bf16x8*>(
          &Pw[lr * 64 + (((ks * 4 + lg) ^ lx) * 8)]);
#pragma unroll
      for (int nf = 0; nf < 4; ++nf) {
        const int rv = nf * 16 + lr;
        bf16x8 vfr = *reinterpret_cast<const bf16x8*>(
            &Vb[rv * 64 + (((ks * 4 + lg) ^ lx) * 8)]);
        o[nf] = mfma16(pa, vfr, o[nf]);
      }
    }
    __builtin_amdgcn_s_setprio(0);
    if (pf) {
      __syncthreads();   // all waves done reading Kb/Vb for this chunk
      *reinterpret_cast<int4*>(&Kb[rs * 64 + sw0]) = ka;
      *reinterpret_cast<int4*>(&Kb[rs * 64 + sw1]) = kb2;
      *reinterpret_cast<int4*>(&Vb[rs * 64 + sw0]) = va;
      *reinterpret_cast<int4*>(&Vb[rs * 64 + sw1]) = vb2;
      __syncthreads();   // staged data visible
    }
  }
  // single cross-lane reduction at the end
  llp += __shfl_xor(llp, 16);
  llp += __shfl_xor(llp, 32);
  float rinv[4];
#pragma unroll
  for (int r = 0; r < 4; ++r)
    rinv[r] = __builtin_amdgcn_rcpf(__shfl(llp, lg * 4 + r, 64));
#pragma unroll
  for (int nf = 0; nf < 4; ++nf)
#pragma unroll
    for (int r = 0; r < 4; ++r) {
      float val = o[nf][r] * rinv[r];
      ctx[((size_t)b * S_ + q0 + lg * 4 + r) * H_ + h * DH_ + nf * 16 + lr] =
          f2bf(val);
    }
}

extern "C" void kernel_launch(void* const* d_in, const int* in_sizes, int n_in,
                              void* d_out, int out_size, void* d_ws, size_t ws_size,
                              hipStream_t stream) {
  const int B = in_sizes[0] / (S_ * H_);   // 4
  const int M = B * S_;                    // 4096
  const float* v    = (const float*)d_in[0];
  const float* k    = (const float*)d_in[1];
  const float* q    = (const float*)d_in[2];
  const int*   mask = (const int*)d_in[3];
  const float* graph= (const float*)d_in[4];
  const float* Wq   = (const float*)d_in[5];
  const float* bq   = (const float*)d_in[6];
  const float* Wk   = (const float*)d_in[7];
  const float* bk   = (const float*)d_in[8];
  const float* Wv   = (const float*)d_in[9];
  const float* bv   = (const float*)d_in[10];
  const float* Wm   = (const float*)d_in[11];
  const float* bm   = (const float*)d_in[12];

  short* ws = (short*)d_ws;
  const size_t WSZ = (size_t)H_ * H_;     // 1M elems per transposed weight
  const size_t TSZ = (size_t)M * H_;      // 4M elems per activation tensor
  short* WqT = ws;
  short* WkT = ws + WSZ;
  short* WvT = ws + 2 * WSZ;
  short* WmT = ws + 3 * WSZ;
  short* Qh  = ws + 4 * WSZ;
  short* Kh  = Qh + TSZ;
  short* VhT = Kh + TSZ;
  short* ctx = VhT + TSZ;
  if (ws_size < (4 * WSZ + 4 * TSZ) * sizeof(short)) {
    fprintf(stderr, "kernel_launch: ws too small (%zu)\n", ws_size);
    return;
  }

  transpose_w<<<dim3(H_ / 64, H_ / 64, 4), 256, 0, stream>>>(
      Wq, Wk, Wv, Wm, WqT, WkT, WvT, WmT);
  qkv128f<<<dim3(M / 128, H_ / 128, 3), 256, 0, stream>>>(
      q, k, v, WqT, WkT, WvT, bq, bk, bv, Qh, Kh, VhT);
  attn<<<dim3(1024), 256, 0, stream>>>(Qh, Kh, VhT, graph, mask, ctx);
  out64<<<dim3(M / 64, H_ / 128), 256, 0, stream>>>(
      ctx, WmT, bm, (float*)d_out);
}